// Round 10
// baseline (97.066 us; speedup 1.0000x reference)
//
#include <hip/hip_runtime.h>
#include <hip/hip_bf16.h>

#define BB 16
#define TT 2048
#define DIMC 512
#define HEADH 64

typedef __attribute__((ext_vector_type(8))) short short8v;   // 8 bf16 (4 VGPRs)
typedef __attribute__((ext_vector_type(4))) float f32x4;     // MFMA C/D

static __device__ __forceinline__ unsigned short f2bf(float f) {
    __hip_bfloat16 h = __float2bfloat16(f);          // RNE, native path
    unsigned short u;
    __builtin_memcpy(&u, &h, 2);
    return u;
}
static __device__ __forceinline__ unsigned int packbf(float lo, float hi) {
    float2 f2; f2.x = lo; f2.y = hi;
    __hip_bfloat162 h2 = __float22bfloat162_rn(f2);
    unsigned int u;
    __builtin_memcpy(&u, &h2, 4);
    return u;
}
// raw v_exp_f32 (log2 domain; args <= 0, flush-to-zero is fine for softmax)
#define EXP2R __builtin_amdgcn_exp2f
// async global->LDS, 16B per lane; LDS dest = wave-uniform base + lane*16
static __device__ __forceinline__ void async_copy16(void* lds, const void* g) {
    __builtin_amdgcn_global_load_lds(
        (const __attribute__((address_space(1))) unsigned char*)g,
        (__attribute__((address_space(3))) unsigned char*)lds, 16, 0, 0);
}

union bfrag {
    unsigned int u[4];
    short8v v;
};

// ---------------- Kernel 0: W f32 -> bf16, concat [q|k|v] rows -------------
__global__ __launch_bounds__(256) void wcvt_kernel(
    const float* __restrict__ Wq, const float* __restrict__ Wk,
    const float* __restrict__ Wv, unsigned short* __restrict__ wb)
{
    const int idx = blockIdx.x * 256 + threadIdx.x;   // 12288 threads x 8 elems
    const int e   = idx << 3;
    const int row = e >> 9, col = e & 511;
    const float* src = (row < 64) ? Wq : (row < 128) ? Wk : Wv;
    const float* p = src + (size_t)(row & 63) * DIMC + col;
    float4 a = *(const float4*)p;
    float4 b = *(const float4*)(p + 4);
    uint4 o;
    o.x = packbf(a.x, a.y); o.y = packbf(a.z, a.w);
    o.z = packbf(b.x, b.y); o.w = packbf(b.z, b.w);
    *(uint4*)(wb + e) = o;
}

// ---------------- Kernel A: MFMA QKV projection + rotary, LDS-staged --------
// (unchanged from round 9: 80 -> ~24us; counters to be read next round)
__global__ __launch_bounds__(256, 2) void qkv_mfma_kernel(
    const float* __restrict__ x,
    const unsigned short* __restrict__ wb,
    const float* __restrict__ fxr, const float* __restrict__ fxi,
    const float* __restrict__ fyr, const float* __restrict__ fyi,
    unsigned short* __restrict__ qo, unsigned short* __restrict__ ko,
    unsigned short* __restrict__ vt)
{
    __shared__ unsigned char xlds[16384];     // [2][64][32] f32, dbuf

    const int tid = threadIdx.x;
    const int w   = tid >> 6;                 // wave -> h-tile triple
    const int l   = tid & 63;
    const int q   = l & 15;
    const int g   = l >> 4;
    const int t0  = blockIdx.x << 6;          // 64 t-rows per block

    f32x4 acc[3][4];
    #pragma unroll
    for (int j = 0; j < 3; ++j)
        #pragma unroll
        for (int tt = 0; tt < 4; ++tt) acc[j][tt] = (f32x4){0.f, 0.f, 0.f, 0.f};

    const unsigned short* wp0 = wb + ((size_t)((3 * w + 0) * 16 + q)) * DIMC + 8 * g;
    const unsigned short* wp1 = wb + ((size_t)((3 * w + 1) * 16 + q)) * DIMC + 8 * g;
    const unsigned short* wp2 = wb + ((size_t)((3 * w + 2) * 16 + q)) * DIMC + 8 * g;

    const int rl = l >> 3;                    // 0..7 row-in-call
    const int cb = (l & 7) ^ rl;              // source col-block (involution)
    const float* xsrc0 = x + (size_t)(t0 + 16 * w + 0 + rl) * DIMC + 4 * cb;
    const float* xsrc1 = x + (size_t)(t0 + 16 * w + 8 + rl) * DIMC + 4 * cb;
    unsigned char* xdst0 = xlds + (16 * w + 0) * 128;   // wave-uniform bases
    unsigned char* xdst1 = xlds + (16 * w + 8) * 128;

#define STAGE_X(bufsel, k0) do {                                              \
        async_copy16(xdst0 + (bufsel) * 8192, xsrc0 + (k0));                  \
        async_copy16(xdst1 + (bufsel) * 8192, xsrc1 + (k0));                  \
    } while (0)

    STAGE_X(0, 0);
    __syncthreads();

    int cur = 0;
    for (int it = 0; it < 16; ++it) {
        const int k0 = it << 5;
        if (it < 15) STAGE_X(cur ^ 1, k0 + 32);

        short8v wf0 = *(const short8v*)(wp0 + k0);
        short8v wf1 = *(const short8v*)(wp1 + k0);
        short8v wf2 = *(const short8v*)(wp2 + k0);

        const unsigned char* xb = xlds + cur * 8192;
        #pragma unroll
        for (int tt = 0; tt < 4; ++tt) {
            const int rr = tt * 16 + q;
            const int s0 = (2 * g)     ^ (q & 7);
            const int s1 = (2 * g + 1) ^ (q & 7);
            float4 f0 = *(const float4*)(xb + rr * 128 + s0 * 16);
            float4 f1 = *(const float4*)(xb + rr * 128 + s1 * 16);
            bfrag xv;
            xv.u[0] = packbf(f0.x, f0.y); xv.u[1] = packbf(f0.z, f0.w);
            xv.u[2] = packbf(f1.x, f1.y); xv.u[3] = packbf(f1.z, f1.w);
            acc[0][tt] = __builtin_amdgcn_mfma_f32_16x16x32_bf16(wf0, xv.v, acc[0][tt], 0, 0, 0);
            acc[1][tt] = __builtin_amdgcn_mfma_f32_16x16x32_bf16(wf1, xv.v, acc[1][tt], 0, 0, 0);
            acc[2][tt] = __builtin_amdgcn_mfma_f32_16x16x32_bf16(wf2, xv.v, acc[2][tt], 0, 0, 0);
        }

        __syncthreads();                      // nxt resident; cur reads done
        cur ^= 1;
    }

    const float qscale = 1.4426950408889634f / 22.627416997969522f; // log2e/sqrt(512)
    #pragma unroll
    for (int j = 0; j < 3; ++j) {
        const int gt   = 3 * w + j;           // global h-tile 0..11
        const int mat  = gt >> 2;             // 0=q, 1=k, 2=v
        const int hbase = (gt & 3) * 16 + 4 * g;
        #pragma unroll
        for (int tt = 0; tt < 4; ++tt) {
            const int trow = t0 + tt * 16 + q;
            const int tl   = trow & (TT - 1);
            if (mat == 2) {
                const int b = trow >> 11;
                #pragma unroll
                for (int r = 0; r < 4; ++r)
                    vt[((size_t)(b * HEADH) + hbase + r) * TT + tl] = f2bf(acc[j][tt][r]);
            } else {
                const float sc = (mat == 0) ? qscale : 1.f;
                unsigned short* dst = ((mat == 0) ? qo : ko) + (size_t)trow * HEADH;
                const int half = hbase >> 5;
                const float* frt = half ? fyr : fxr;
                const float* fit = half ? fyi : fxi;
                const int pi0 = (hbase & 31) >> 1;
                float fr0 = frt[tl * 16 + pi0],     fi0 = fit[tl * 16 + pi0];
                float fr1 = frt[tl * 16 + pi0 + 1], fi1 = fit[tl * 16 + pi0 + 1];
                float e0 = acc[j][tt][0] * fr0 - acc[j][tt][1] * fi0;
                float e1 = acc[j][tt][0] * fi0 + acc[j][tt][1] * fr0;
                float e2 = acc[j][tt][2] * fr1 - acc[j][tt][3] * fi1;
                float e3 = acc[j][tt][2] * fi1 + acc[j][tt][3] * fr1;
                uint2 ow;
                ow.x = packbf(e0 * sc, e1 * sc);
                ow.y = packbf(e2 * sc, e3 * sc);
                *(uint2*)(dst + hbase) = ow;
            }
        }
    }
#undef STAGE_X
}

// ---------------- Kernel B: MFMA flash attention ----------------------------
// Round 10: V staging dropped (LDS 40K -> 24K). r9 counters: occupancy 17%
// (LDS-capped 2 blocks/CU) with MfmaUtil 14 / VALU 35 / HBM 10 -> latency-
// bound. V fragments now load direct global->reg (r6-verified path):
// contiguous 16B/lane, L2/L3-resident, issued at iter head, consumed at
// iter end (~500cy+ slack). launch_bounds(256,4) -> 4 blocks/CU target.
// psum cross-lane reduce moved after PV issue (off the critical path).
__global__ __launch_bounds__(256, 4) void attn_mfma_kernel(
    const unsigned short* __restrict__ qws,   // [b][t][64] bf16, pre-scaled
    const unsigned short* __restrict__ kws,   // [b][t][64] bf16
    const unsigned short* __restrict__ vtw,   // [b][d][t]  bf16 (V^T)
    float* __restrict__ out)
{
    __shared__ unsigned char smem[24576];     // K dbuf 16K | plds 8K

    const int tid = threadIdx.x;
    const int w   = tid >> 6;                 // wave -> q-subtile
    const int l   = tid & 63;
    const int q   = l & 15;
    const int g   = l >> 4;
    const int b   = blockIdx.x >> 5;
    const int q0  = (blockIdx.x & 31) << 6;   // 64 q-rows per block
    const int qw  = q0 + 16 * w;              // this wave's q base
    const int rx  = q & 7;                    // read-side swizzle
    const int swz = (q & 7) << 2;             // plds swizzle (verified r2-r9)

    const int rl = l >> 3;
    const int sl = (l & 7) ^ rl;              // involution pre-swizzle

    unsigned int* pldsw = (unsigned int*)(smem + 16384 + (w << 11));

    const unsigned short* kbase = kws + (size_t)b * TT * HEADH;
    const unsigned short* vbase = vtw + (size_t)b * HEADH * TT;

    const unsigned short* ksrc0 = kbase + (size_t)(16 * w + rl) * HEADH + 8 * sl;
    const unsigned short* ksrc1 = kbase + (size_t)(16 * w + 8 + rl) * HEADH + 8 * sl;

#define STAGE_K(bufsel, kv)  do {                                             \
        unsigned char* kd = smem + (bufsel) * 8192 + (w << 11);               \
        async_copy16(kd,        ksrc0 + (size_t)(kv) * HEADH);                \
        async_copy16(kd + 1024, ksrc1 + (size_t)(kv) * HEADH);                \
    } while (0)

    short8v qf0, qf1;
    {
        const unsigned short* qp = qws + ((size_t)(b * TT + qw + q)) * HEADH + 8 * g;
        qf0 = *(const short8v*)(qp);
        qf1 = *(const short8v*)(qp + 32);
    }

    f32x4 oacc[4];
    #pragma unroll
    for (int mt = 0; mt < 4; ++mt) oacc[mt] = (f32x4){0.f, 0.f, 0.f, 0.f};
    float m = -1e30f, lsum = 0.f;

    STAGE_K(0, 0);
    __syncthreads();                          // tile 0 resident

    int cur = 0;
    for (int it = 0; it < 32; ++it) {
        const int kv0 = it << 6;
        if (it < 31) STAGE_K(cur ^ 1, kv0 + 64);

        // ---- V fragments direct global->reg (r6-verified layout) ----
        short8v vf[2][4];
        #pragma unroll
        for (int s = 0; s < 2; ++s)
            #pragma unroll
            for (int mt = 0; mt < 4; ++mt)
                vf[s][mt] = *(const short8v*)(vbase +
                    (size_t)(16 * mt + q) * TT + kv0 + 32 * s + 8 * g);

        const unsigned char* kb = smem + cur * 8192;

        // ---- QK^T from LDS ----
        f32x4 sacc[4];
        #pragma unroll
        for (int n = 0; n < 4; ++n) {
            const int r = 16 * n + q;
            const short8v k0 = *(const short8v*)(kb + r * 128 + ((g ^ rx) << 4));
            const short8v k1 = *(const short8v*)(kb + r * 128 + (((4 + g) ^ rx) << 4));
            f32x4 z = (f32x4){0.f, 0.f, 0.f, 0.f};
            z = __builtin_amdgcn_mfma_f32_16x16x32_bf16(k0, qf0, z, 0, 0, 0);
            z = __builtin_amdgcn_mfma_f32_16x16x32_bf16(k1, qf1, z, 0, 0, 0);
            sacc[n] = z;
        }

        // ---- online softmax (lane owns q-row qw + (l&15)) ----
        float cmax = sacc[0][0];
        #pragma unroll
        for (int n = 0; n < 4; ++n)
            #pragma unroll
            for (int r = 0; r < 4; ++r) cmax = fmaxf(cmax, sacc[n][r]);
        cmax = fmaxf(cmax, __shfl_xor(cmax, 16));
        cmax = fmaxf(cmax, __shfl_xor(cmax, 32));
        const float mnew = fmaxf(m, cmax);

        float p[4][4];
        #pragma unroll
        for (int n = 0; n < 4; ++n) {
            #pragma unroll
            for (int r = 0; r < 4; ++r)
                p[n][r] = EXP2R(sacc[n][r] - mnew);   // raw v_exp_f32
            uint2 wv;
            wv.x = packbf(p[n][0], p[n][1]);
            wv.y = packbf(p[n][2], p[n][3]);
            *(uint2*)&pldsw[q * 32 + ((8 * n + 2 * g) ^ swz)] = wv;
        }

        const float sc = EXP2R(m - mnew);
        if (__any(cmax > m)) {
            #pragma unroll
            for (int mt = 0; mt < 4; ++mt)
                #pragma unroll
                for (int r = 0; r < 4; ++r) oacc[mt][r] *= sc;
        }

        // ---- PV: out^T += V^T . P^T ----
        #pragma unroll
        for (int s = 0; s < 2; ++s) {
            const short8v pb = *(const short8v*)&pldsw[q * 32 + ((16 * s + 4 * g) ^ swz)];
            #pragma unroll
            for (int mt = 0; mt < 4; ++mt)
                oacc[mt] = __builtin_amdgcn_mfma_f32_16x16x32_bf16(vf[s][mt], pb,
                                                                   oacc[mt], 0, 0, 0);
        }

        // ---- psum reduce off the critical path (only feeds lsum) ----
        float psum = 0.f;
        #pragma unroll
        for (int n = 0; n < 4; ++n)
            #pragma unroll
            for (int r = 0; r < 4; ++r) psum += p[n][r];
        psum += __shfl_xor(psum, 16);
        psum += __shfl_xor(psum, 32);
        lsum = lsum * sc + psum;
        m = mnew;

        __syncthreads();                      // nxt K resident; cur reads done
        cur ^= 1;
    }

    // ---- normalize + store: oacc[mt][r] = out[qw+q][16mt+4g+r] ----
    const float inv = 1.f / lsum;
    float* op = out + ((size_t)(b * TT + qw + q)) * HEADH;
    #pragma unroll
    for (int mt = 0; mt < 4; ++mt) {
        float4 v4 = make_float4(oacc[mt][0] * inv, oacc[mt][1] * inv,
                                oacc[mt][2] * inv, oacc[mt][3] * inv);
        *(float4*)(op + 16 * mt + 4 * g) = v4;
    }
#undef STAGE_K
}

extern "C" void kernel_launch(void* const* d_in, const int* in_sizes, int n_in,
                              void* d_out, int out_size, void* d_ws, size_t ws_size,
                              hipStream_t stream)
{
    const float* x   = (const float*)d_in[0];
    const float* Wq  = (const float*)d_in[1];
    const float* Wk  = (const float*)d_in[2];
    const float* Wv  = (const float*)d_in[3];
    const float* fxr = (const float*)d_in[4];
    const float* fxi = (const float*)d_in[5];
    const float* fyr = (const float*)d_in[6];
    const float* fyi = (const float*)d_in[7];
    float* out = (float*)d_out;

    unsigned short* qo = (unsigned short*)d_ws;                  // 4 MB
    unsigned short* ko = qo + (size_t)BB * TT * HEADH;           // 4 MB
    unsigned short* vt = ko + (size_t)BB * TT * HEADH;           // 4 MB
    unsigned short* wb = vt + (size_t)BB * TT * HEADH;           // 192 KB

    wcvt_kernel<<<48, 256, 0, stream>>>(Wq, Wk, Wv, wb);
    qkv_mfma_kernel<<<(BB * TT) / 64, 256, 0, stream>>>(x, wb, fxr, fxi, fyr, fyi,
                                                        qo, ko, vt);
    attn_mfma_kernel<<<BB * 32, 256, 0, stream>>>(qo, ko, vt, out);
}

// Round 11
// 69.781 us; speedup vs baseline: 1.3910x; 1.3910x over previous
//
#include <hip/hip_runtime.h>
#include <hip/hip_bf16.h>

#define BB 16
#define TT 2048
#define DIMC 512
#define HEADH 64

typedef __attribute__((ext_vector_type(8))) short short8v;   // 8 bf16 (4 VGPRs)
typedef __attribute__((ext_vector_type(4))) float f32x4;     // MFMA C/D

static __device__ __forceinline__ unsigned short f2bf(float f) {
    __hip_bfloat16 h = __float2bfloat16(f);          // RNE, native path
    unsigned short u;
    __builtin_memcpy(&u, &h, 2);
    return u;
}
static __device__ __forceinline__ unsigned int packbf(float lo, float hi) {
    float2 f2; f2.x = lo; f2.y = hi;
    __hip_bfloat162 h2 = __float22bfloat162_rn(f2);
    unsigned int u;
    __builtin_memcpy(&u, &h2, 4);
    return u;
}
// raw v_exp_f32 (log2 domain; args <= 0, flush-to-zero is fine for softmax)
#define EXP2R __builtin_amdgcn_exp2f
// async global->LDS, 16B per lane; LDS dest = wave-uniform base + lane*16
static __device__ __forceinline__ void async_copy16(void* lds, const void* g) {
    __builtin_amdgcn_global_load_lds(
        (const __attribute__((address_space(1))) unsigned char*)g,
        (__attribute__((address_space(3))) unsigned char*)lds, 16, 0, 0);
}

union bfrag {
    unsigned int u[4];
    short8v v;
};

// ---------------- Kernel 0: W f32 -> bf16, concat [q|k|v] rows -------------
__global__ __launch_bounds__(256) void wcvt_kernel(
    const float* __restrict__ Wq, const float* __restrict__ Wk,
    const float* __restrict__ Wv, unsigned short* __restrict__ wb)
{
    const int idx = blockIdx.x * 256 + threadIdx.x;   // 12288 threads x 8 elems
    const int e   = idx << 3;
    const int row = e >> 9, col = e & 511;
    const float* src = (row < 64) ? Wq : (row < 128) ? Wk : Wv;
    const float* p = src + (size_t)(row & 63) * DIMC + col;
    float4 a = *(const float4*)p;
    float4 b = *(const float4*)(p + 4);
    uint4 o;
    o.x = packbf(a.x, a.y); o.y = packbf(a.z, a.w);
    o.z = packbf(b.x, b.y); o.w = packbf(b.z, b.w);
    *(uint4*)(wb + e) = o;
}

// ---------------- Kernel A: MFMA QKV projection + rotary, LDS-staged --------
// (unchanged from round 9: verified ~24us)
__global__ __launch_bounds__(256, 2) void qkv_mfma_kernel(
    const float* __restrict__ x,
    const unsigned short* __restrict__ wb,
    const float* __restrict__ fxr, const float* __restrict__ fxi,
    const float* __restrict__ fyr, const float* __restrict__ fyi,
    unsigned short* __restrict__ qo, unsigned short* __restrict__ ko,
    unsigned short* __restrict__ vt)
{
    __shared__ unsigned char xlds[16384];     // [2][64][32] f32, dbuf

    const int tid = threadIdx.x;
    const int w   = tid >> 6;                 // wave -> h-tile triple
    const int l   = tid & 63;
    const int q   = l & 15;
    const int g   = l >> 4;
    const int t0  = blockIdx.x << 6;          // 64 t-rows per block

    f32x4 acc[3][4];
    #pragma unroll
    for (int j = 0; j < 3; ++j)
        #pragma unroll
        for (int tt = 0; tt < 4; ++tt) acc[j][tt] = (f32x4){0.f, 0.f, 0.f, 0.f};

    const unsigned short* wp0 = wb + ((size_t)((3 * w + 0) * 16 + q)) * DIMC + 8 * g;
    const unsigned short* wp1 = wb + ((size_t)((3 * w + 1) * 16 + q)) * DIMC + 8 * g;
    const unsigned short* wp2 = wb + ((size_t)((3 * w + 2) * 16 + q)) * DIMC + 8 * g;

    const int rl = l >> 3;                    // 0..7 row-in-call
    const int cb = (l & 7) ^ rl;              // source col-block (involution)
    const float* xsrc0 = x + (size_t)(t0 + 16 * w + 0 + rl) * DIMC + 4 * cb;
    const float* xsrc1 = x + (size_t)(t0 + 16 * w + 8 + rl) * DIMC + 4 * cb;
    unsigned char* xdst0 = xlds + (16 * w + 0) * 128;   // wave-uniform bases
    unsigned char* xdst1 = xlds + (16 * w + 8) * 128;

#define STAGE_X(bufsel, k0) do {                                              \
        async_copy16(xdst0 + (bufsel) * 8192, xsrc0 + (k0));                  \
        async_copy16(xdst1 + (bufsel) * 8192, xsrc1 + (k0));                  \
    } while (0)

    STAGE_X(0, 0);
    __syncthreads();

    int cur = 0;
    for (int it = 0; it < 16; ++it) {
        const int k0 = it << 5;
        if (it < 15) STAGE_X(cur ^ 1, k0 + 32);

        short8v wf0 = *(const short8v*)(wp0 + k0);
        short8v wf1 = *(const short8v*)(wp1 + k0);
        short8v wf2 = *(const short8v*)(wp2 + k0);

        const unsigned char* xb = xlds + cur * 8192;
        #pragma unroll
        for (int tt = 0; tt < 4; ++tt) {
            const int rr = tt * 16 + q;
            const int s0 = (2 * g)     ^ (q & 7);
            const int s1 = (2 * g + 1) ^ (q & 7);
            float4 f0 = *(const float4*)(xb + rr * 128 + s0 * 16);
            float4 f1 = *(const float4*)(xb + rr * 128 + s1 * 16);
            bfrag xv;
            xv.u[0] = packbf(f0.x, f0.y); xv.u[1] = packbf(f0.z, f0.w);
            xv.u[2] = packbf(f1.x, f1.y); xv.u[3] = packbf(f1.z, f1.w);
            acc[0][tt] = __builtin_amdgcn_mfma_f32_16x16x32_bf16(wf0, xv.v, acc[0][tt], 0, 0, 0);
            acc[1][tt] = __builtin_amdgcn_mfma_f32_16x16x32_bf16(wf1, xv.v, acc[1][tt], 0, 0, 0);
            acc[2][tt] = __builtin_amdgcn_mfma_f32_16x16x32_bf16(wf2, xv.v, acc[2][tt], 0, 0, 0);
        }

        __syncthreads();                      // nxt resident; cur reads done
        cur ^= 1;
    }

    const float qscale = 1.4426950408889634f / 22.627416997969522f; // log2e/sqrt(512)
    #pragma unroll
    for (int j = 0; j < 3; ++j) {
        const int gt   = 3 * w + j;           // global h-tile 0..11
        const int mat  = gt >> 2;             // 0=q, 1=k, 2=v
        const int hbase = (gt & 3) * 16 + 4 * g;
        #pragma unroll
        for (int tt = 0; tt < 4; ++tt) {
            const int trow = t0 + tt * 16 + q;
            const int tl   = trow & (TT - 1);
            if (mat == 2) {
                const int b = trow >> 11;
                #pragma unroll
                for (int r = 0; r < 4; ++r)
                    vt[((size_t)(b * HEADH) + hbase + r) * TT + tl] = f2bf(acc[j][tt][r]);
            } else {
                const float sc = (mat == 0) ? qscale : 1.f;
                unsigned short* dst = ((mat == 0) ? qo : ko) + (size_t)trow * HEADH;
                const int half = hbase >> 5;
                const float* frt = half ? fyr : fxr;
                const float* fit = half ? fyi : fxi;
                const int pi0 = (hbase & 31) >> 1;
                float fr0 = frt[tl * 16 + pi0],     fi0 = fit[tl * 16 + pi0];
                float fr1 = frt[tl * 16 + pi0 + 1], fi1 = fit[tl * 16 + pi0 + 1];
                float e0 = acc[j][tt][0] * fr0 - acc[j][tt][1] * fi0;
                float e1 = acc[j][tt][0] * fi0 + acc[j][tt][1] * fr0;
                float e2 = acc[j][tt][2] * fr1 - acc[j][tt][3] * fi1;
                float e3 = acc[j][tt][2] * fi1 + acc[j][tt][3] * fr1;
                uint2 ow;
                ow.x = packbf(e0 * sc, e1 * sc);
                ow.y = packbf(e2 * sc, e3 * sc);
                *(uint2*)(dst + hbase) = ow;
            }
        }
    }
#undef STAGE_X
}

// ---------------- Kernel B: MFMA flash attention, KVBLK=128 -----------------
// Round 11: revert to r9's all-LDS-staged structure (r10's V-direct stalled
// on shared vmcnt: waiting V drained the K prefetch mid-iter), then halve
// the iteration count: KVBLK 64 -> 128 with ONE softmax pass per 128 scores.
// 16 iters: half the barrier+drain events, half the per-row softmax
// bookkeeping, 2x within-iter ILP. Occupancy is grid-capped at 2 blocks/CU
// (512 blocks), so LDS 80KB (K dbuf 32K | V^T dbuf 32K | plds 16K) costs
// nothing. All fragment maps are the r9-verified ones extended to n<8, s<4.
__global__ __launch_bounds__(256, 2) void attn_mfma_kernel(
    const unsigned short* __restrict__ qws,   // [b][t][64] bf16, pre-scaled
    const unsigned short* __restrict__ kws,   // [b][t][64] bf16
    const unsigned short* __restrict__ vtw,   // [b][d][t]  bf16 (V^T)
    float* __restrict__ out)
{
    __shared__ unsigned char smem[81920];     // K 2x16K | V 2x16K | plds 16K

    const int tid = threadIdx.x;
    const int w   = tid >> 6;                 // wave -> q-subtile
    const int l   = tid & 63;
    const int q   = l & 15;
    const int g   = l >> 4;
    const int b   = blockIdx.x >> 5;
    const int q0  = (blockIdx.x & 31) << 6;   // 64 q-rows per block
    const int qw  = q0 + 16 * w;              // this wave's q base
    const int rx  = q & 7;                    // read-side swizzle (K rows, V rows)
    const int swz = (q & 7) << 2;             // plds swizzle

    const int rl = l >> 3;                    // K staging: row-in-call
    const int sl = (l & 7) ^ rl;              // K source col-block (involution)
    const int vr = l >> 4;                    // V staging: d-row-in-call 0..3
    const int ve = (l & 15) ^ vr;             // V source t-block, even calls
    const int vo = (l & 15) ^ (4 + vr);       // V source t-block, odd calls

    unsigned int* pldsw = (unsigned int*)(smem + 65536 + (w << 12)); // 4KB/wave

    const unsigned short* kbase = kws + (size_t)b * TT * HEADH;
    const unsigned short* vbase = vtw + (size_t)b * HEADH * TT;

    // K: wave w stages tile rows 32w..32w+31 (4 calls x 8 rows x 128B)
    const unsigned short* ksrc = kbase + (size_t)(32 * w + rl) * HEADH + 8 * sl;
    // V: wave w stages d-rows 16w..16w+15 (4 calls x 4 rows x 256B)
    const unsigned short* vsrcE = vbase + (size_t)(16 * w + vr) * TT + 8 * ve;
    const unsigned short* vsrcO = vbase + (size_t)(16 * w + vr) * TT + 8 * vo;

#define STAGE_TILE(bufsel, kv)  do {                                          \
        unsigned char* kd = smem + (bufsel) * 16384 + (w << 12);              \
        async_copy16(kd,        ksrc + (size_t)((kv) +  0) * HEADH);          \
        async_copy16(kd + 1024, ksrc + (size_t)((kv) +  8) * HEADH);          \
        async_copy16(kd + 2048, ksrc + (size_t)((kv) + 16) * HEADH);          \
        async_copy16(kd + 3072, ksrc + (size_t)((kv) + 24) * HEADH);          \
        unsigned char* vd = smem + 32768 + (bufsel) * 16384 + (w << 12);      \
        async_copy16(vd,        vsrcE + (kv));                                \
        async_copy16(vd + 1024, vsrcO + (kv) + 4 * TT);                       \
        async_copy16(vd + 2048, vsrcE + (kv) + 8 * TT);                       \
        async_copy16(vd + 3072, vsrcO + (kv) + 12 * TT);                      \
    } while (0)

    short8v qf0, qf1;
    {
        const unsigned short* qp = qws + ((size_t)(b * TT + qw + q)) * HEADH + 8 * g;
        qf0 = *(const short8v*)(qp);
        qf1 = *(const short8v*)(qp + 32);
    }

    f32x4 oacc[4];
    #pragma unroll
    for (int mt = 0; mt < 4; ++mt) oacc[mt] = (f32x4){0.f, 0.f, 0.f, 0.f};
    float m = -1e30f, lsum = 0.f;

    STAGE_TILE(0, 0);
    __syncthreads();                          // tile 0 resident

    int cur = 0;
    for (int it = 0; it < 16; ++it) {
        const int kv0 = it << 7;
        if (it < 15) STAGE_TILE(cur ^ 1, kv0 + 128);

        const unsigned char* kb = smem + cur * 16384;
        const unsigned char* vb = smem + 32768 + cur * 16384;

        // ---- QK^T from LDS: 8 kv-subtiles x 2 k-steps ----
        f32x4 sacc[8];
        #pragma unroll
        for (int n = 0; n < 8; ++n) {
            const int r = 16 * n + q;
            const short8v k0 = *(const short8v*)(kb + r * 128 + ((g ^ rx) << 4));
            const short8v k1 = *(const short8v*)(kb + r * 128 + (((4 + g) ^ rx) << 4));
            f32x4 z = (f32x4){0.f, 0.f, 0.f, 0.f};
            z = __builtin_amdgcn_mfma_f32_16x16x32_bf16(k0, qf0, z, 0, 0, 0);
            z = __builtin_amdgcn_mfma_f32_16x16x32_bf16(k1, qf1, z, 0, 0, 0);
            sacc[n] = z;
        }

        // ---- single online-softmax pass over 128 scores ----
        float cmax = sacc[0][0];
        #pragma unroll
        for (int n = 0; n < 8; ++n)
            #pragma unroll
            for (int r = 0; r < 4; ++r) cmax = fmaxf(cmax, sacc[n][r]);
        cmax = fmaxf(cmax, __shfl_xor(cmax, 16));
        cmax = fmaxf(cmax, __shfl_xor(cmax, 32));
        const float mnew = fmaxf(m, cmax);

        float p[8][4];
        #pragma unroll
        for (int n = 0; n < 8; ++n) {
            #pragma unroll
            for (int r = 0; r < 4; ++r)
                p[n][r] = EXP2R(sacc[n][r] - mnew);   // raw v_exp_f32
            uint2 wv;
            wv.x = packbf(p[n][0], p[n][1]);
            wv.y = packbf(p[n][2], p[n][3]);
            *(uint2*)&pldsw[q * 64 + ((8 * n + 2 * g) ^ swz)] = wv;
        }

        const float sc = EXP2R(m - mnew);
        if (__any(cmax > m)) {
            #pragma unroll
            for (int mt = 0; mt < 4; ++mt)
                #pragma unroll
                for (int r = 0; r < 4; ++r) oacc[mt][r] *= sc;
        }

        // ---- PV: out^T += V^T . P^T  (4 k-steps x 4 d-tiles) ----
        #pragma unroll
        for (int s = 0; s < 4; ++s) {
            const short8v pb = *(const short8v*)&pldsw[q * 64 + ((16 * s + 4 * g) ^ swz)];
            #pragma unroll
            for (int mt = 0; mt < 4; ++mt) {
                const int d = 16 * mt + q;
                const short8v vfr = *(const short8v*)(vb + d * 256 + (((4 * s + g) ^ rx) << 4));
                oacc[mt] = __builtin_amdgcn_mfma_f32_16x16x32_bf16(vfr, pb, oacc[mt], 0, 0, 0);
            }
        }

        // ---- psum reduce off the critical path ----
        float psum = 0.f;
        #pragma unroll
        for (int n = 0; n < 8; ++n)
            #pragma unroll
            for (int r = 0; r < 4; ++r) psum += p[n][r];
        psum += __shfl_xor(psum, 16);
        psum += __shfl_xor(psum, 32);
        lsum = lsum * sc + psum;
        m = mnew;

        __syncthreads();                      // nxt resident; cur reads done
        cur ^= 1;
    }

    // ---- normalize + store: oacc[mt][r] = out[qw+q][16mt+4g+r] ----
    const float inv = 1.f / lsum;
    float* op = out + ((size_t)(b * TT + qw + q)) * HEADH;
    #pragma unroll
    for (int mt = 0; mt < 4; ++mt) {
        float4 v4 = make_float4(oacc[mt][0] * inv, oacc[mt][1] * inv,
                                oacc[mt][2] * inv, oacc[mt][3] * inv);
        *(float4*)(op + 16 * mt + 4 * g) = v4;
    }
#undef STAGE_TILE
}

extern "C" void kernel_launch(void* const* d_in, const int* in_sizes, int n_in,
                              void* d_out, int out_size, void* d_ws, size_t ws_size,
                              hipStream_t stream)
{
    const float* x   = (const float*)d_in[0];
    const float* Wq  = (const float*)d_in[1];
    const float* Wk  = (const float*)d_in[2];
    const float* Wv  = (const float*)d_in[3];
    const float* fxr = (const float*)d_in[4];
    const float* fxi = (const float*)d_in[5];
    const float* fyr = (const float*)d_in[6];
    const float* fyi = (const float*)d_in[7];
    float* out = (float*)d_out;

    unsigned short* qo = (unsigned short*)d_ws;                  // 4 MB
    unsigned short* ko = qo + (size_t)BB * TT * HEADH;           // 4 MB
    unsigned short* vt = ko + (size_t)BB * TT * HEADH;           // 4 MB
    unsigned short* wb = vt + (size_t)BB * TT * HEADH;           // 192 KB

    wcvt_kernel<<<48, 256, 0, stream>>>(Wq, Wk, Wv, wb);
    qkv_mfma_kernel<<<(BB * TT) / 64, 256, 0, stream>>>(x, wb, fxr, fxi, fyr, fyi,
                                                        qo, ko, vt);
    attn_mfma_kernel<<<BB * 32, 256, 0, stream>>>(qo, ko, vt, out);
}